// Round 1
// baseline (1444.633 us; speedup 1.0000x reference)
//
#include <hip/hip_runtime.h>
#include <hip/hip_bf16.h>

#define NNODES 50000
#define NEDGES 800000
#define DIM 128
#define HEADS 8
#define FFNDIM 512

// ---------------- embedding: h = ent_tab[ent_ids] + pos_tab[arw_pos] ----------------
__global__ void k_embed(const int* __restrict__ ent_ids, const int* __restrict__ arw_pos,
                        const float* __restrict__ ent_tab, const float* __restrict__ pos_tab,
                        float* __restrict__ h) {
  int t = blockIdx.x * 256 + threadIdx.x;   // over N*32 float4s
  if (t >= NNODES * 32) return;
  int n = t >> 5, c = t & 31;
  float4 a = ((const float4*)ent_tab)[ent_ids[n] * 32 + c];
  float4 b = ((const float4*)pos_tab)[arw_pos[n] * 32 + c];
  ((float4*)h)[t] = make_float4(a.x + b.x, a.y + b.y, a.z + b.z, a.w + b.w);
}

// ---------------- Vr[d][h] = sum_k Wr[d][h*16+k] * ar[h][k] ----------------
__global__ void k_vr(const float* __restrict__ Wr, const float* __restrict__ ar,
                     float* __restrict__ vr) {
  for (int i = threadIdx.x; i < 1024; i += 256) {
    int d = i >> 3, hh = i & 7;
    float s = 0.f;
    #pragma unroll
    for (int k = 0; k < 16; ++k) s += Wr[d * 128 + hh * 16 + k] * ar[hh * 16 + k];
    vr[i] = s;
  }
}

// ---------------- relsc[r][h] = sum_d rel_tab[r][d] * vr[d][h] ----------------
__global__ void k_relsc(const float* __restrict__ rel_tab, const float* __restrict__ vr,
                        float* __restrict__ relsc) {
  int t = blockIdx.x * 256 + threadIdx.x;
  if (t >= 500 * 8) return;
  int r = t >> 3, hh = t & 7;
  float s = 0.f;
  for (int d = 0; d < 128; ++d) s += rel_tab[r * 128 + d] * vr[d * 8 + hh];
  relsc[t] = s;
}

// ---------------- CSR build ----------------
__global__ void k_hist(const int* __restrict__ dst, int* __restrict__ deg) {
  int e = blockIdx.x * 256 + threadIdx.x;
  if (e < NEDGES) atomicAdd(&deg[dst[e]], 1);
}

__global__ void k_scan(const int* __restrict__ deg, int* __restrict__ rowptr,
                       int* __restrict__ cursor) {
  __shared__ int sh[1024];
  __shared__ int s_run;
  int tid = threadIdx.x;
  if (tid == 0) s_run = 0;
  __syncthreads();
  for (int base = 0; base < NNODES; base += 1024) {
    int i = base + tid;
    int v = (i < NNODES) ? deg[i] : 0;
    sh[tid] = v;
    __syncthreads();
    int x = v;
    for (int off = 1; off < 1024; off <<= 1) {
      int t = (tid >= off) ? sh[tid - off] : 0;
      __syncthreads();
      x += t;
      sh[tid] = x;
      __syncthreads();
    }
    int run = s_run;                    // value from previous chunk (barrier above)
    if (i < NNODES) { rowptr[i] = run + x - v; cursor[i] = run + x - v; }
    __syncthreads();
    if (tid == 1023) s_run = run + x;
    __syncthreads();
  }
  if (tid == 0) rowptr[NNODES] = s_run;
}

__global__ void k_scatter(const int* __restrict__ dst, const int* __restrict__ src,
                          const int* __restrict__ rel_ids, int* __restrict__ cursor,
                          int* __restrict__ srcs, int* __restrict__ rels) {
  int e = blockIdx.x * 256 + threadIdx.x;
  if (e >= NEDGES) return;
  int p = atomicAdd(&cursor[dst[e]], 1);
  srcs[p] = src[e];
  rels[p] = rel_ids[e];
}

// ---------------- f = h @ Wh (+ s_src/s_dst epilogue) ----------------
__global__ __launch_bounds__(256) void k_fgemm(
    const float* __restrict__ hin, const float* __restrict__ W,
    const float* __restrict__ ah, const float* __restrict__ at,
    float* __restrict__ fout, float* __restrict__ ssrc, float* __restrict__ sdst) {
  __shared__ float sW[32 * 128];        // 16KB K-chunk of W
  __shared__ float sH[32 * 132];        // padded stride 132 (bank-spread)
  int tid = threadIdx.x;
  int row0 = blockIdx.x * 32;
  for (int i = tid; i < 1024; i += 256) {
    int r = i >> 5, c = i & 31;
    float4 v = make_float4(0.f, 0.f, 0.f, 0.f);
    if (row0 + r < NNODES) v = ((const float4*)hin)[(row0 + r) * 32 + c];
    *(float4*)&sH[r * 132 + c * 4] = v;
  }
  int colg = tid & 15, rowg = tid >> 4;
  int col0 = colg * 8;
  int r0 = rowg * 2;
  float acc[2][8] = {};
  for (int kc = 0; kc < 4; ++kc) {
    __syncthreads();
    for (int i = tid; i < 1024; i += 256)
      ((float4*)sW)[i] = ((const float4*)W)[kc * 1024 + i];
    __syncthreads();
    #pragma unroll 4
    for (int kk = 0; kk < 32; ++kk) {
      int k = kc * 32 + kk;
      float a0 = sH[r0 * 132 + k];
      float a1 = sH[(r0 + 1) * 132 + k];
      float4 wa = *(const float4*)&sW[kk * 128 + col0];
      float4 wb = *(const float4*)&sW[kk * 128 + col0 + 4];
      float w[8] = {wa.x, wa.y, wa.z, wa.w, wb.x, wb.y, wb.z, wb.w};
      #pragma unroll
      for (int c2 = 0; c2 < 8; ++c2) { acc[0][c2] += a0 * w[c2]; acc[1][c2] += a1 * w[c2]; }
    }
  }
  int head = colg >> 1;
  int koff = (colg & 1) * 8;
  #pragma unroll
  for (int rr = 0; rr < 2; ++rr) {
    int r = row0 + r0 + rr;
    if (r < NNODES) {
      *(float4*)&fout[r * 128 + col0] =
          make_float4(acc[rr][0], acc[rr][1], acc[rr][2], acc[rr][3]);
      *(float4*)&fout[r * 128 + col0 + 4] =
          make_float4(acc[rr][4], acc[rr][5], acc[rr][6], acc[rr][7]);
      float ps = 0.f, pt = 0.f;
      #pragma unroll
      for (int c2 = 0; c2 < 8; ++c2) {
        ps += acc[rr][c2] * ah[head * 16 + koff + c2];
        pt += acc[rr][c2] * at[head * 16 + koff + c2];
      }
      ps += __shfl_xor(ps, 1);
      pt += __shfl_xor(pt, 1);
      if ((colg & 1) == 0) { ssrc[r * 8 + head] = ps; sdst[r * 8 + head] = pt; }
    }
  }
}

// ---------------- edge softmax (per dst node, wave-per-node) ----------------
__global__ void k_softmax(const int* __restrict__ rowptr, const int* __restrict__ srcs,
                          const int* __restrict__ rels, const float* __restrict__ ssrc,
                          const float* __restrict__ sdst, const float* __restrict__ relsc,
                          float* __restrict__ att) {
  int lane = threadIdx.x & 63, wid = threadIdx.x >> 6;
  int n = blockIdx.x * 4 + wid;
  if (n >= NNODES) return;
  int start = rowptr[n], end = rowptr[n + 1];
  if (start == end) return;
  int hh = lane & 7, jj = lane >> 3;
  float sd = sdst[n * 8 + hh];
  float m = -1e30f;
  for (int j0 = start; j0 < end; j0 += 8) {
    int j = j0 + jj;
    float e = -1e30f;
    if (j < end) {
      int s = srcs[j];
      e = ssrc[s * 8 + hh] + sd;
      if (relsc) e += relsc[rels[j] * 8 + hh];
      e = (e >= 0.f) ? e : 0.2f * e;      // leaky relu
      att[j * 8 + hh] = e;
    }
    m = fmaxf(m, e);
  }
  m = fmaxf(m, __shfl_xor(m, 8));
  m = fmaxf(m, __shfl_xor(m, 16));
  m = fmaxf(m, __shfl_xor(m, 32));
  float den = 0.f;
  for (int j0 = start; j0 < end; j0 += 8) {
    int j = j0 + jj;
    if (j < end) {
      float ex = expf(att[j * 8 + hh] - m);
      att[j * 8 + hh] = ex;
      den += ex;
    }
  }
  den += __shfl_xor(den, 8);
  den += __shfl_xor(den, 16);
  den += __shfl_xor(den, 32);
  float inv = 1.f / (den + 1e-16f);
  for (int j0 = start; j0 < end; j0 += 8) {
    int j = j0 + jj;
    if (j < end) att[j * 8 + hh] *= inv;
  }
}

// ---------------- diffusion hop: out = a*f0 + (1-a)*agg(att * fin[src]) ----------------
__global__ void k_hop(const int* __restrict__ rowptr, const int* __restrict__ srcs,
                      const float* __restrict__ att, const float* __restrict__ fin,
                      const float* __restrict__ f0, float* __restrict__ fout) {
  int lane = threadIdx.x & 63, wid = threadIdx.x >> 6;
  int n = blockIdx.x * 4 + wid;
  if (n >= NNODES) return;
  int start = rowptr[n], end = rowptr[n + 1];
  int hsel = lane >> 3;
  float ax = 0.f, ay = 0.f;
  const float2* fin2 = (const float2*)fin;
  for (int j = start; j < end; ++j) {
    int s = srcs[j];
    float a = att[j * 8 + hsel];
    float2 v = fin2[s * 64 + lane];
    ax += a * v.x;
    ay += a * v.y;
  }
  float2 z = ((const float2*)f0)[n * 64 + lane];
  ((float2*)fout)[n * 64 + lane] =
      make_float2(0.15f * z.x + 0.85f * ax, 0.15f * z.y + 0.85f * ay);
}

// ---------------- LayerNorm (optional residual) ----------------
__global__ void k_ln(const float* __restrict__ x, const float* __restrict__ resid,
                     const float* __restrict__ g, const float* __restrict__ b,
                     float* __restrict__ out) {
  int lane = threadIdx.x & 63, wid = threadIdx.x >> 6;
  int n = blockIdx.x * 4 + wid;
  if (n >= NNODES) return;
  float2 v = ((const float2*)x)[n * 64 + lane];
  if (resid) {
    float2 r = ((const float2*)resid)[n * 64 + lane];
    v.x += r.x; v.y += r.y;
  }
  float s = v.x + v.y;
  #pragma unroll
  for (int o = 1; o < 64; o <<= 1) s += __shfl_xor(s, o);
  float mean = s * (1.f / 128.f);
  float dx = v.x - mean, dy = v.y - mean;
  float q = dx * dx + dy * dy;
  #pragma unroll
  for (int o = 1; o < 64; o <<= 1) q += __shfl_xor(q, o);
  float rs = rsqrtf(q * (1.f / 128.f) + 1e-5f);
  float2 gb = ((const float2*)g)[lane];
  float2 bb = ((const float2*)b)[lane];
  ((float2*)out)[n * 64 + lane] =
      make_float2(dx * rs * gb.x + bb.x, dy * rs * gb.y + bb.y);
}

// ---------------- fused FFN: out = relu(o@w1+c1)@w2 + c2 + o (pre-LN sum) ----------------
__global__ __launch_bounds__(256) void k_ffn(
    const float* __restrict__ oin, const float* __restrict__ w1, const float* __restrict__ c1,
    const float* __restrict__ w2, const float* __restrict__ c2, float* __restrict__ out) {
  __shared__ float sO[16 * 128];   // 8KB: o tile; later w2 chunks
  __shared__ float sW[16 * 512];   // 32KB: w1 chunks; later T
  int tid = threadIdx.x;
  int row0 = blockIdx.x * 16;
  for (int i = tid; i < 512; i += 256) {
    int r = i >> 5, c = i & 31;
    float4 v = make_float4(0.f, 0.f, 0.f, 0.f);
    if (row0 + r < NNODES) v = ((const float4*)oin)[(row0 + r) * 32 + c];
    ((float4*)sO)[i] = v;
  }
  int colg = tid & 31, rowg = tid >> 5;
  float acc[2][16] = {};
  // phase 1: T = relu(O @ w1 + c1), K=128 in 8 chunks of 16
  for (int kc = 0; kc < 8; ++kc) {
    __syncthreads();
    for (int i = tid; i < 2048; i += 256)
      ((float4*)sW)[i] = ((const float4*)w1)[kc * 2048 + i];
    __syncthreads();
    #pragma unroll 4
    for (int kk = 0; kk < 16; ++kk) {
      int k = kc * 16 + kk;
      float a0 = sO[(rowg * 2) * 128 + k];
      float a1 = sO[(rowg * 2 + 1) * 128 + k];
      #pragma unroll
      for (int i = 0; i < 4; ++i) {
        float4 w = *(const float4*)&sW[kk * 512 + colg * 4 + 128 * i];
        acc[0][i * 4 + 0] += a0 * w.x; acc[0][i * 4 + 1] += a0 * w.y;
        acc[0][i * 4 + 2] += a0 * w.z; acc[0][i * 4 + 3] += a0 * w.w;
        acc[1][i * 4 + 0] += a1 * w.x; acc[1][i * 4 + 1] += a1 * w.y;
        acc[1][i * 4 + 2] += a1 * w.z; acc[1][i * 4 + 3] += a1 * w.w;
      }
    }
  }
  __syncthreads();
  // T = relu(acc + c1) into sW region, layout T[r][c] at sW[r*512 + c]
  #pragma unroll
  for (int i = 0; i < 4; ++i) {
    float4 bias = *(const float4*)&c1[colg * 4 + 128 * i];
    #pragma unroll
    for (int rr = 0; rr < 2; ++rr) {
      float4 t = make_float4(fmaxf(acc[rr][i * 4 + 0] + bias.x, 0.f),
                             fmaxf(acc[rr][i * 4 + 1] + bias.y, 0.f),
                             fmaxf(acc[rr][i * 4 + 2] + bias.z, 0.f),
                             fmaxf(acc[rr][i * 4 + 3] + bias.w, 0.f));
      *(float4*)&sW[(rowg * 2 + rr) * 512 + colg * 4 + 128 * i] = t;
    }
  }
  // residual for phase-2 mapping (rows rowg*2..+1, cols colg*4..+3)
  float4 res0 = *(const float4*)&sO[(rowg * 2) * 128 + colg * 4];
  float4 res1 = *(const float4*)&sO[(rowg * 2 + 1) * 128 + colg * 4];
  __syncthreads();
  // phase 2: out = T @ w2, K=512 in 32 chunks of 16 (w2 chunks staged into sO region)
  float a2[2][4] = {};
  for (int kc = 0; kc < 32; ++kc) {
    __syncthreads();
    for (int i = tid; i < 512; i += 256)
      ((float4*)sO)[i] = ((const float4*)w2)[kc * 512 + i];
    __syncthreads();
    #pragma unroll 4
    for (int kk = 0; kk < 16; ++kk) {
      float t0 = sW[(rowg * 2) * 512 + kc * 16 + kk];
      float t1 = sW[(rowg * 2 + 1) * 512 + kc * 16 + kk];
      float4 w = *(const float4*)&sO[kk * 128 + colg * 4];
      a2[0][0] += t0 * w.x; a2[0][1] += t0 * w.y; a2[0][2] += t0 * w.z; a2[0][3] += t0 * w.w;
      a2[1][0] += t1 * w.x; a2[1][1] += t1 * w.y; a2[1][2] += t1 * w.z; a2[1][3] += t1 * w.w;
    }
  }
  float4 bias2 = *(const float4*)&c2[colg * 4];
  #pragma unroll
  for (int rr = 0; rr < 2; ++rr) {
    int r = row0 + rowg * 2 + rr;
    if (r < NNODES) {
      float4 rs = (rr == 0) ? res0 : res1;
      float4 o4 = make_float4(a2[rr][0] + bias2.x + rs.x, a2[rr][1] + bias2.y + rs.y,
                              a2[rr][2] + bias2.z + rs.z, a2[rr][3] + bias2.w + rs.w);
      *(float4*)&out[r * 128 + colg * 4] = o4;
    }
  }
}

// ---------------- final gather ----------------
__global__ void k_gather(const int* __restrict__ ids, const float* __restrict__ h,
                         float* __restrict__ out) {
  int t = blockIdx.x * 256 + threadIdx.x;   // 512*32
  if (t >= 512 * 32) return;
  int b = t >> 5, c = t & 31;
  ((float4*)out)[t] = ((const float4*)h)[ids[b] * 32 + c];
}

// ---------------- host side ----------------
struct LayerW {
  const float *Wh, *ah, *at, *g1, *b1, *w1, *c1, *w2, *c2, *g2, *b2;
};

static void run_layer(float* h, float* f0, float* fa, float* fb, float* o,
                      float* ssrc, float* sdst, float* att, const float* relsc,
                      const int* rowptr, const int* srcs, const int* rels,
                      const LayerW& L, hipStream_t stream) {
  k_fgemm<<<(NNODES + 31) / 32, 256, 0, stream>>>(h, L.Wh, L.ah, L.at, f0, ssrc, sdst);
  k_softmax<<<(NNODES + 3) / 4, 256, 0, stream>>>(rowptr, srcs, rels, ssrc, sdst, relsc, att);
  k_hop<<<(NNODES + 3) / 4, 256, 0, stream>>>(rowptr, srcs, att, f0, f0, fa);
  k_hop<<<(NNODES + 3) / 4, 256, 0, stream>>>(rowptr, srcs, att, fa, f0, fb);
  k_hop<<<(NNODES + 3) / 4, 256, 0, stream>>>(rowptr, srcs, att, fb, f0, fa);
  k_ln<<<(NNODES + 3) / 4, 256, 0, stream>>>(fa, h, L.g1, L.b1, o);
  k_ffn<<<NNODES / 16, 256, 0, stream>>>(o, L.w1, L.c1, L.w2, L.c2, f0);
  k_ln<<<(NNODES + 3) / 4, 256, 0, stream>>>(f0, nullptr, L.g2, L.b2, h);
}

extern "C" void kernel_launch(void* const* d_in, const int* in_sizes, int n_in,
                              void* d_out, int out_size, void* d_ws, size_t ws_size,
                              hipStream_t stream) {
  const int* ent_ids   = (const int*)d_in[0];
  const int* rel_ids   = (const int*)d_in[1];
  const int* arw_pos   = (const int*)d_in[2];
  const int* src       = (const int*)d_in[3];
  const int* dst       = (const int*)d_in[4];
  const int* batch_ids = (const int*)d_in[5];
  const float* ent_tab = (const float*)d_in[6];
  const float* rel_tab = (const float*)d_in[7];
  const float* pos_tab = (const float*)d_in[8];

  LayerW L0 = {(const float*)d_in[9],  (const float*)d_in[11], (const float*)d_in[12],
               (const float*)d_in[14], (const float*)d_in[15], (const float*)d_in[16],
               (const float*)d_in[17], (const float*)d_in[18], (const float*)d_in[19],
               (const float*)d_in[20], (const float*)d_in[21]};
  const float* l0_Wr = (const float*)d_in[10];
  const float* l0_ar = (const float*)d_in[13];
  LayerW L1 = {(const float*)d_in[22], (const float*)d_in[23], (const float*)d_in[24],
               (const float*)d_in[25], (const float*)d_in[26], (const float*)d_in[27],
               (const float*)d_in[28], (const float*)d_in[29], (const float*)d_in[30],
               (const float*)d_in[31], (const float*)d_in[32]};

  // workspace carve (≈164 MB)
  float* p = (float*)d_ws;
  float* h     = p; p += NNODES * 128;
  float* f0    = p; p += NNODES * 128;
  float* fa    = p; p += NNODES * 128;
  float* fb    = p; p += NNODES * 128;
  float* o     = p; p += NNODES * 128;
  float* ssrc  = p; p += NNODES * 8;
  float* sdst  = p; p += NNODES * 8;
  float* att   = p; p += NEDGES * 8;
  float* relsc = p; p += 500 * 8;
  float* vr    = p; p += 1024;
  int* deg     = (int*)p;
  int* rowptr  = deg + NNODES;
  int* cursor  = rowptr + NNODES + 1;
  int* srcs    = cursor + NNODES;
  int* rels    = srcs + NEDGES;

  // embeddings + relation score table
  k_embed<<<(NNODES * 32) / 256, 256, 0, stream>>>(ent_ids, arw_pos, ent_tab, pos_tab, h);
  k_vr<<<1, 256, 0, stream>>>(l0_Wr, l0_ar, vr);
  k_relsc<<<16, 256, 0, stream>>>(rel_tab, vr, relsc);

  // CSR by dst
  hipMemsetAsync(deg, 0, NNODES * sizeof(int), stream);
  k_hist<<<NEDGES / 256, 256, 0, stream>>>(dst, deg);
  k_scan<<<1, 1024, 0, stream>>>(deg, rowptr, cursor);
  k_scatter<<<NEDGES / 256, 256, 0, stream>>>(dst, src, rel_ids, cursor, srcs, rels);

  run_layer(h, f0, fa, fb, o, ssrc, sdst, att, relsc, rowptr, srcs, rels, L0, stream);
  run_layer(h, f0, fa, fb, o, ssrc, sdst, att, nullptr, rowptr, srcs, rels, L1, stream);

  k_gather<<<64, 256, 0, stream>>>(batch_ids, h, (float*)d_out);
}

// Round 2
// 920.342 us; speedup vs baseline: 1.5697x; 1.5697x over previous
//
#include <hip/hip_runtime.h>
#include <hip/hip_bf16.h>

#define NNODES 50000
#define NEDGES 800000
#define NP 50048            // 391 * 128, padded node count for unguarded GEMM tiles
#define DIM 128
#define HEADS 8
#define FFNDIM 512

typedef __bf16 bf16x8 __attribute__((ext_vector_type(8)));
typedef float f32x4 __attribute__((ext_vector_type(4)));
typedef unsigned int uint32;
typedef unsigned short ushort16;

__device__ __forceinline__ float b2f(uint32 u) {
  union { uint32 i; float f; } x; x.i = u << 16; return x.f;
}
__device__ __forceinline__ ushort16 f2b(float f) {
  __bf16 h = (__bf16)f; return __builtin_bit_cast(ushort16, h);
}

// ---------------- embedding: hb = bf16(ent_tab[ent_ids] + pos_tab[arw_pos]) ----------------
__global__ void k_embed(const int* __restrict__ ent_ids, const int* __restrict__ arw_pos,
                        const float* __restrict__ ent_tab, const float* __restrict__ pos_tab,
                        __bf16* __restrict__ hb) {
  int t = blockIdx.x * 256 + threadIdx.x;   // over N*32 float4s
  if (t >= NNODES * 32) return;
  int n = t >> 5, c = t & 31;
  float4 a = ((const float4*)ent_tab)[ent_ids[n] * 32 + c];
  float4 b = ((const float4*)pos_tab)[arw_pos[n] * 32 + c];
  ushort4 o;
  o.x = f2b(a.x + b.x); o.y = f2b(a.y + b.y);
  o.z = f2b(a.z + b.z); o.w = f2b(a.w + b.w);
  ((ushort4*)hb)[t] = o;
}

// ---------------- weight transpose+convert: Wt[c][r] = bf16(W[r][c]) ----------------
__global__ void k_wt(const float* __restrict__ W, __bf16* __restrict__ Wt, int R, int C) {
  int c = blockIdx.x * 16 + (threadIdx.x & 15);
  int r = blockIdx.y * 16 + (threadIdx.x >> 4);
  if (r < R && c < C) Wt[(long)c * R + r] = (__bf16)W[(long)r * C + c];
}

// ---------------- Vr[d][h] = sum_k Wr[d][h*16+k] * ar[h][k] ----------------
__global__ void k_vr(const float* __restrict__ Wr, const float* __restrict__ ar,
                     float* __restrict__ vr) {
  for (int i = threadIdx.x; i < 1024; i += 256) {
    int d = i >> 3, hh = i & 7;
    float s = 0.f;
    #pragma unroll
    for (int k = 0; k < 16; ++k) s += Wr[d * 128 + hh * 16 + k] * ar[hh * 16 + k];
    vr[i] = s;
  }
}

// ---------------- relsc[r][h] = sum_d rel_tab[r][d] * vr[d][h] ----------------
__global__ void k_relsc(const float* __restrict__ rel_tab, const float* __restrict__ vr,
                        float* __restrict__ relsc) {
  int t = blockIdx.x * 256 + threadIdx.x;
  if (t >= 500 * 8) return;
  int r = t >> 3, hh = t & 7;
  float s = 0.f;
  for (int d = 0; d < 128; ++d) s += rel_tab[r * 128 + d] * vr[d * 8 + hh];
  relsc[t] = s;
}

// ---------------- CSR build ----------------
__global__ void k_hist(const int* __restrict__ dst, int* __restrict__ deg) {
  int e = blockIdx.x * 256 + threadIdx.x;
  if (e < NEDGES) atomicAdd(&deg[dst[e]], 1);
}

__global__ void k_scan(const int* __restrict__ deg, int* __restrict__ rowptr,
                       int* __restrict__ cursor) {
  __shared__ int sh[1024];
  __shared__ int s_run;
  int tid = threadIdx.x;
  if (tid == 0) s_run = 0;
  __syncthreads();
  for (int base = 0; base < NNODES; base += 1024) {
    int i = base + tid;
    int v = (i < NNODES) ? deg[i] : 0;
    sh[tid] = v;
    __syncthreads();
    int x = v;
    for (int off = 1; off < 1024; off <<= 1) {
      int t = (tid >= off) ? sh[tid - off] : 0;
      __syncthreads();
      x += t;
      sh[tid] = x;
      __syncthreads();
    }
    int run = s_run;
    if (i < NNODES) { rowptr[i] = run + x - v; cursor[i] = run + x - v; }
    __syncthreads();
    if (tid == 1023) s_run = run + x;
    __syncthreads();
  }
  if (tid == 0) rowptr[NNODES] = s_run;
}

__global__ void k_scatter(const int* __restrict__ dst, const int* __restrict__ src,
                          const int* __restrict__ rel_ids, int* __restrict__ cursor,
                          int* __restrict__ srcs, int* __restrict__ rels) {
  int e = blockIdx.x * 256 + threadIdx.x;
  if (e >= NEDGES) return;
  int p = atomicAdd(&cursor[dst[e]], 1);
  srcs[p] = src[e];
  rels[p] = rel_ids[e];
}

// ---------------- MFMA GEMM: C[M,NB] = A[M,KDIM] @ Bt[NB,KDIM]^T, epilogues ----------------
// EPI 0: outb = bf16(acc)                       (f = h @ Wh)
// EPI 1: outb = bf16(relu(acc + bias[c]))       (T = relu(o @ w1 + c1))
// EPI 2: outf = acc + bias[c] + resid_bf16      (y = T @ w2 + c2 + o)
template<int KDIM, int NB, int EPI>
__global__ __launch_bounds__(256) void k_gemm(
    const __bf16* __restrict__ A, const __bf16* __restrict__ Bt,
    const float* __restrict__ bias, const __bf16* __restrict__ resid,
    __bf16* __restrict__ outb, float* __restrict__ outf) {
  __shared__ char sA[16384];   // 128 rows x 64 bf16, XOR-swizzled
  __shared__ char sB[16384];
  const int tid = threadIdx.x;
  const int lane = tid & 63, wid = tid >> 6;
  const int wr = wid >> 1, wc = wid & 1;
  const int lr = lane & 15, hi = lane >> 4;
  const long row0 = (long)blockIdx.x * 128;
  const long col0 = (long)blockIdx.y * 128;
  f32x4 acc[4][4] = {};

  for (int kc = 0; kc < KDIM / 64; ++kc) {
    __syncthreads();
    #pragma unroll
    for (int i = 0; i < 4; ++i) {
      int q = i * 256 + tid;            // 1024 16B chunks per tile
      int r = q >> 3, slot = q & 7;
      int sw = ((slot ^ (r & 7)) << 4); // swizzled byte offset within 128B row
      int4 av = *(const int4*)(A + (row0 + r) * KDIM + kc * 64 + slot * 8);
      *(int4*)(sA + r * 128 + sw) = av;
      int4 bv = *(const int4*)(Bt + (col0 + r) * KDIM + kc * 64 + slot * 8);
      *(int4*)(sB + r * 128 + sw) = bv;
    }
    __syncthreads();
    #pragma unroll
    for (int ks = 0; ks < 2; ++ks) {
      bf16x8 af[4], bfr[4];
      #pragma unroll
      for (int m = 0; m < 4; ++m) {
        int r = wr * 64 + m * 16 + lr;
        int cb = ((ks * 4 + hi) ^ (r & 7)) << 4;
        af[m] = *(const bf16x8*)(sA + r * 128 + cb);
      }
      #pragma unroll
      for (int n = 0; n < 4; ++n) {
        int r = wc * 64 + n * 16 + lr;
        int cb = ((ks * 4 + hi) ^ (r & 7)) << 4;
        bfr[n] = *(const bf16x8*)(sB + r * 128 + cb);
      }
      #pragma unroll
      for (int m = 0; m < 4; ++m)
        #pragma unroll
        for (int n = 0; n < 4; ++n)
          acc[m][n] = __builtin_amdgcn_mfma_f32_16x16x32_bf16(af[m], bfr[n], acc[m][n], 0, 0, 0);
    }
  }

  // C layout per frag: col = lane&15, row = (lane>>4)*4 + j  (m89-verified)
  #pragma unroll
  for (int m = 0; m < 4; ++m) {
    #pragma unroll
    for (int j = 0; j < 4; ++j) {
      long r = row0 + wr * 64 + m * 16 + hi * 4 + j;
      #pragma unroll
      for (int n = 0; n < 4; ++n) {
        long c = col0 + wc * 64 + n * 16 + lr;
        float v = acc[m][n][j];
        if (EPI == 0) {
          outb[r * NB + c] = (__bf16)v;
        } else if (EPI == 1) {
          outb[r * NB + c] = (__bf16)fmaxf(v + bias[c], 0.f);
        } else {
          outf[r * NB + c] = v + bias[c] + (float)resid[r * NB + c];
        }
      }
    }
  }
}

// ---------------- per-node attention scores from f (bf16) ----------------
__global__ void k_scores(const __bf16* __restrict__ f, const float* __restrict__ ah,
                         const float* __restrict__ at, float* __restrict__ ssrc,
                         float* __restrict__ sdst) {
  int lane = threadIdx.x & 63, wid = threadIdx.x >> 6;
  int n = blockIdx.x * 4 + wid;
  if (n >= NNODES) return;
  uint32 v = ((const uint32*)f)[n * 64 + lane];
  float x = b2f(v & 0xffffu), y = b2f(v >> 16);
  float2 a = ((const float2*)ah)[lane];
  float2 t = ((const float2*)at)[lane];
  float ps = x * a.x + y * a.y;
  float pt = x * t.x + y * t.y;
  #pragma unroll
  for (int o = 1; o < 8; o <<= 1) { ps += __shfl_xor(ps, o); pt += __shfl_xor(pt, o); }
  if ((lane & 7) == 0) {
    ssrc[n * 8 + (lane >> 3)] = ps;
    sdst[n * 8 + (lane >> 3)] = pt;
  }
}

// ---------------- edge softmax (per dst node, wave-per-node) ----------------
__global__ void k_softmax(const int* __restrict__ rowptr, const int* __restrict__ srcs,
                          const int* __restrict__ rels, const float* __restrict__ ssrc,
                          const float* __restrict__ sdst, const float* __restrict__ relsc,
                          float* __restrict__ att) {
  int lane = threadIdx.x & 63, wid = threadIdx.x >> 6;
  int n = blockIdx.x * 4 + wid;
  if (n >= NNODES) return;
  int start = rowptr[n], end = rowptr[n + 1];
  if (start == end) return;
  int hh = lane & 7, jj = lane >> 3;
  float sd = sdst[n * 8 + hh];
  float m = -1e30f;
  for (int j0 = start; j0 < end; j0 += 8) {
    int j = j0 + jj;
    float e = -1e30f;
    if (j < end) {
      int s = srcs[j];
      e = ssrc[s * 8 + hh] + sd;
      if (relsc) e += relsc[rels[j] * 8 + hh];
      e = (e >= 0.f) ? e : 0.2f * e;
      att[j * 8 + hh] = e;
    }
    m = fmaxf(m, e);
  }
  m = fmaxf(m, __shfl_xor(m, 8));
  m = fmaxf(m, __shfl_xor(m, 16));
  m = fmaxf(m, __shfl_xor(m, 32));
  float den = 0.f;
  for (int j0 = start; j0 < end; j0 += 8) {
    int j = j0 + jj;
    if (j < end) {
      float ex = expf(att[j * 8 + hh] - m);
      att[j * 8 + hh] = ex;
      den += ex;
    }
  }
  den += __shfl_xor(den, 8);
  den += __shfl_xor(den, 16);
  den += __shfl_xor(den, 32);
  float inv = 1.f / (den + 1e-16f);
  for (int j0 = start; j0 < end; j0 += 8) {
    int j = j0 + jj;
    if (j < end) att[j * 8 + hh] *= inv;
  }
}

// ---------------- diffusion hop (bf16 feats, fp32 accum) ----------------
__global__ void k_hop(const int* __restrict__ rowptr, const int* __restrict__ srcs,
                      const float* __restrict__ att, const __bf16* __restrict__ fin,
                      const __bf16* __restrict__ f0, __bf16* __restrict__ fout) {
  int lane = threadIdx.x & 63, wid = threadIdx.x >> 6;
  int n = blockIdx.x * 4 + wid;
  if (n >= NNODES) return;
  int start = rowptr[n], end = rowptr[n + 1];
  int hsel = lane >> 3;
  float ax = 0.f, ay = 0.f;
  const uint32* fin2 = (const uint32*)fin;
  for (int j = start; j < end; ++j) {
    int s = srcs[j];
    float a = att[j * 8 + hsel];
    uint32 v = fin2[s * 64 + lane];
    ax += a * b2f(v & 0xffffu);
    ay += a * b2f(v >> 16);
  }
  uint32 z = ((const uint32*)f0)[n * 64 + lane];
  float ox = 0.15f * b2f(z & 0xffffu) + 0.85f * ax;
  float oy = 0.15f * b2f(z >> 16) + 0.85f * ay;
  ((uint32*)fout)[n * 64 + lane] = ((uint32)f2b(oy) << 16) | (uint32)f2b(ox);
}

// ---------------- LayerNorm ----------------
// INBF=1: x bf16 + resid bf16; INBF=0: x fp32, no resid. Outputs optional fp32/bf16.
template<int INBF>
__global__ void k_ln(const void* __restrict__ xin, const __bf16* __restrict__ resid,
                     const float* __restrict__ g, const float* __restrict__ b,
                     float* __restrict__ outf, __bf16* __restrict__ outb) {
  int lane = threadIdx.x & 63, wid = threadIdx.x >> 6;
  int n = blockIdx.x * 4 + wid;
  if (n >= NNODES) return;
  float x, y;
  if (INBF) {
    uint32 v = ((const uint32*)xin)[n * 64 + lane];
    uint32 r = ((const uint32*)resid)[n * 64 + lane];
    x = b2f(v & 0xffffu) + b2f(r & 0xffffu);
    y = b2f(v >> 16) + b2f(r >> 16);
  } else {
    float2 v = ((const float2*)xin)[n * 64 + lane];
    x = v.x; y = v.y;
  }
  float s = x + y;
  #pragma unroll
  for (int o = 1; o < 64; o <<= 1) s += __shfl_xor(s, o);
  float mean = s * (1.f / 128.f);
  float dx = x - mean, dy = y - mean;
  float q = dx * dx + dy * dy;
  #pragma unroll
  for (int o = 1; o < 64; o <<= 1) q += __shfl_xor(q, o);
  float rs = rsqrtf(q * (1.f / 128.f) + 1e-5f);
  float2 gg = ((const float2*)g)[lane];
  float2 bb = ((const float2*)b)[lane];
  float ox = dx * rs * gg.x + bb.x;
  float oy = dy * rs * gg.y + bb.y;
  if (outf) ((float2*)outf)[n * 64 + lane] = make_float2(ox, oy);
  if (outb) ((uint32*)outb)[n * 64 + lane] = ((uint32)f2b(oy) << 16) | (uint32)f2b(ox);
}

// ---------------- final gather (fp32) ----------------
__global__ void k_gather(const int* __restrict__ ids, const float* __restrict__ h,
                         float* __restrict__ out) {
  int t = blockIdx.x * 256 + threadIdx.x;   // 512*32
  if (t >= 512 * 32) return;
  int b = t >> 5, c = t & 31;
  ((float4*)out)[t] = ((const float4*)h)[(long)ids[b] * 32 + c];
}

// ---------------- host side ----------------
struct LayerW {
  const float *Wh, *ah, *at, *g1, *b1, *w1, *c1, *w2, *c2, *g2, *b2;
};

extern "C" void kernel_launch(void* const* d_in, const int* in_sizes, int n_in,
                              void* d_out, int out_size, void* d_ws, size_t ws_size,
                              hipStream_t stream) {
  const int* ent_ids   = (const int*)d_in[0];
  const int* rel_ids   = (const int*)d_in[1];
  const int* arw_pos   = (const int*)d_in[2];
  const int* src       = (const int*)d_in[3];
  const int* dst       = (const int*)d_in[4];
  const int* batch_ids = (const int*)d_in[5];
  const float* ent_tab = (const float*)d_in[6];
  const float* rel_tab = (const float*)d_in[7];
  const float* pos_tab = (const float*)d_in[8];

  LayerW L0 = {(const float*)d_in[9],  (const float*)d_in[11], (const float*)d_in[12],
               (const float*)d_in[14], (const float*)d_in[15], (const float*)d_in[16],
               (const float*)d_in[17], (const float*)d_in[18], (const float*)d_in[19],
               (const float*)d_in[20], (const float*)d_in[21]};
  const float* l0_Wr = (const float*)d_in[10];
  const float* l0_ar = (const float*)d_in[13];
  LayerW L1 = {(const float*)d_in[22], (const float*)d_in[23], (const float*)d_in[24],
               (const float*)d_in[25], (const float*)d_in[26], (const float*)d_in[27],
               (const float*)d_in[28], (const float*)d_in[29], (const float*)d_in[30],
               (const float*)d_in[31], (const float*)d_in[32]};

  // ---- workspace carve (~130 MB) ----
  char* p = (char*)d_ws;
  auto alloc = [&](size_t bytes) { char* q = p; p += (bytes + 255) & ~(size_t)255; return q; };
  __bf16* hb = (__bf16*)alloc((size_t)NP * 128 * 2);
  __bf16* f  = (__bf16*)alloc((size_t)NP * 128 * 2);
  __bf16* fb = (__bf16*)alloc((size_t)NP * 128 * 2);   // must follow f (y aliases f+fb)
  __bf16* fa = (__bf16*)alloc((size_t)NP * 128 * 2);
  __bf16* ob = (__bf16*)alloc((size_t)NP * 128 * 2);
  char*   U  = alloc((size_t)NP * 512 * 2);            // union: att (fp32 E*8) | T (bf16 NP*512)
  float*  att = (float*)U;
  __bf16* T   = (__bf16*)U;
  float*  y   = (float*)f;                             // fp32 NP*128, spans f+fb
  float* ssrc  = (float*)alloc((size_t)NP * 8 * 4);
  float* sdst  = (float*)alloc((size_t)NP * 8 * 4);
  float* relsc = (float*)alloc(500 * 8 * 4);
  float* vr    = (float*)alloc(1024 * 4);
  __bf16* Wht0 = (__bf16*)alloc(128 * 128 * 2);
  __bf16* Wht1 = (__bf16*)alloc(128 * 128 * 2);
  __bf16* w1t0 = (__bf16*)alloc(512 * 128 * 2);
  __bf16* w1t1 = (__bf16*)alloc(512 * 128 * 2);
  __bf16* w2t0 = (__bf16*)alloc(128 * 512 * 2);
  __bf16* w2t1 = (__bf16*)alloc(128 * 512 * 2);
  int* deg    = (int*)alloc(NNODES * 4);
  int* rowptr = (int*)alloc((NNODES + 1) * 4);
  int* cursor = (int*)alloc(NNODES * 4);
  int* srcs   = (int*)alloc((size_t)NEDGES * 4);
  int* rels   = (int*)alloc((size_t)NEDGES * 4);

  // pad rows of GEMM A-inputs must be zero (written only here; k_* touch n<NNODES)
  hipMemsetAsync(hb + (size_t)NNODES * 128, 0, (size_t)(NP - NNODES) * 128 * 2, stream);
  hipMemsetAsync(ob + (size_t)NNODES * 128, 0, (size_t)(NP - NNODES) * 128 * 2, stream);

  // embeddings, weight prep, relation score table
  k_embed<<<(NNODES * 32 + 255) / 256, 256, 0, stream>>>(ent_ids, arw_pos, ent_tab, pos_tab, hb);
  k_wt<<<dim3(8, 8), 256, 0, stream>>>(L0.Wh, Wht0, 128, 128);
  k_wt<<<dim3(8, 8), 256, 0, stream>>>(L1.Wh, Wht1, 128, 128);
  k_wt<<<dim3(32, 8), 256, 0, stream>>>(L0.w1, w1t0, 128, 512);
  k_wt<<<dim3(32, 8), 256, 0, stream>>>(L1.w1, w1t1, 128, 512);
  k_wt<<<dim3(8, 32), 256, 0, stream>>>(L0.w2, w2t0, 512, 128);
  k_wt<<<dim3(8, 32), 256, 0, stream>>>(L1.w2, w2t1, 512, 128);
  k_vr<<<1, 256, 0, stream>>>(l0_Wr, l0_ar, vr);
  k_relsc<<<16, 256, 0, stream>>>(rel_tab, vr, relsc);

  // CSR by dst
  hipMemsetAsync(deg, 0, NNODES * sizeof(int), stream);
  k_hist<<<NEDGES / 256, 256, 0, stream>>>(dst, deg);
  k_scan<<<1, 1024, 0, stream>>>(deg, rowptr, cursor);
  k_scatter<<<NEDGES / 256, 256, 0, stream>>>(dst, src, rel_ids, cursor, srcs, rels);

  const int NB4 = (NNODES + 3) / 4;
  for (int L = 0; L < 2; ++L) {
    const LayerW& W = L ? L1 : L0;
    const __bf16* Wht = L ? Wht1 : Wht0;
    const __bf16* w1t = L ? w1t1 : w1t0;
    const __bf16* w2t = L ? w2t1 : w2t0;
    const float* rsc  = L ? nullptr : relsc;

    k_gemm<128, 128, 0><<<dim3(391, 1), 256, 0, stream>>>(hb, Wht, nullptr, nullptr, f, nullptr);
    k_scores<<<NB4, 256, 0, stream>>>(f, W.ah, W.at, ssrc, sdst);
    k_softmax<<<NB4, 256, 0, stream>>>(rowptr, srcs, rels, ssrc, sdst, rsc, att);
    k_hop<<<NB4, 256, 0, stream>>>(rowptr, srcs, att, f, f, fa);
    k_hop<<<NB4, 256, 0, stream>>>(rowptr, srcs, att, fa, f, fb);
    k_hop<<<NB4, 256, 0, stream>>>(rowptr, srcs, att, fb, f, fa);
    k_ln<1><<<NB4, 256, 0, stream>>>(fa, hb, W.g1, W.b1, nullptr, ob);
    k_gemm<128, 512, 1><<<dim3(391, 4), 256, 0, stream>>>(ob, w1t, W.c1, nullptr, T, nullptr);
    k_gemm<512, 128, 2><<<dim3(391, 1), 256, 0, stream>>>(T, w2t, W.c2, ob, nullptr, y);
    k_ln<0><<<NB4, 256, 0, stream>>>(y, nullptr, W.g2, W.b2, y, hb);
  }

  k_gather<<<64, 256, 0, stream>>>(batch_ids, y, (float*)d_out);
}

// Round 3
// 645.756 us; speedup vs baseline: 2.2371x; 1.4252x over previous
//
#include <hip/hip_runtime.h>
#include <hip/hip_bf16.h>

#define NNODES 50000
#define NEDGES 800000
#define NP 50048            // 391 * 128, padded node count for unguarded GEMM tiles
#define DIM 128
#define HEADS 8
#define FFNDIM 512

typedef __bf16 bf16x8 __attribute__((ext_vector_type(8)));
typedef float f32x4 __attribute__((ext_vector_type(4)));
typedef unsigned int uint32;
typedef unsigned short ushort16;

__device__ __forceinline__ float b2f(uint32 u) {
  union { uint32 i; float f; } x; x.i = u << 16; return x.f;
}
__device__ __forceinline__ ushort16 f2b(float f) {
  __bf16 h = (__bf16)f; return __builtin_bit_cast(ushort16, h);
}

// ---------------- embedding: hb = bf16(ent_tab[ent_ids] + pos_tab[arw_pos]) ----------------
__global__ void k_embed(const int* __restrict__ ent_ids, const int* __restrict__ arw_pos,
                        const float* __restrict__ ent_tab, const float* __restrict__ pos_tab,
                        __bf16* __restrict__ hb) {
  int t = blockIdx.x * 256 + threadIdx.x;   // over N*32 float4s
  if (t >= NNODES * 32) return;
  int n = t >> 5, c = t & 31;
  float4 a = ((const float4*)ent_tab)[ent_ids[n] * 32 + c];
  float4 b = ((const float4*)pos_tab)[arw_pos[n] * 32 + c];
  ushort4 o;
  o.x = f2b(a.x + b.x); o.y = f2b(a.y + b.y);
  o.z = f2b(a.z + b.z); o.w = f2b(a.w + b.w);
  ((ushort4*)hb)[t] = o;
}

// ---------------- weight transpose+convert: Wt[c][r] = bf16(W[r][c]) ----------------
__global__ void k_wt(const float* __restrict__ W, __bf16* __restrict__ Wt, int R, int C) {
  int c = blockIdx.x * 16 + (threadIdx.x & 15);
  int r = blockIdx.y * 16 + (threadIdx.x >> 4);
  if (r < R && c < C) Wt[(long)c * R + r] = (__bf16)W[(long)r * C + c];
}

// ---------------- Vr[d][h] = sum_k Wr[d][h*16+k] * ar[h][k] ----------------
__global__ void k_vr(const float* __restrict__ Wr, const float* __restrict__ ar,
                     float* __restrict__ vr) {
  for (int i = threadIdx.x; i < 1024; i += 256) {
    int d = i >> 3, hh = i & 7;
    float s = 0.f;
    #pragma unroll
    for (int k = 0; k < 16; ++k) s += Wr[d * 128 + hh * 16 + k] * ar[hh * 16 + k];
    vr[i] = s;
  }
}

// ---------------- relsc[r][h] = sum_d rel_tab[r][d] * vr[d][h] ----------------
__global__ void k_relsc(const float* __restrict__ rel_tab, const float* __restrict__ vr,
                        float* __restrict__ relsc) {
  int t = blockIdx.x * 256 + threadIdx.x;
  if (t >= 500 * 8) return;
  int r = t >> 3, hh = t & 7;
  float s = 0.f;
  for (int d = 0; d < 128; ++d) s += rel_tab[r * 128 + d] * vr[d * 8 + hh];
  relsc[t] = s;
}

// ---------------- CSR build ----------------
__global__ void k_hist(const int* __restrict__ dst, int* __restrict__ deg) {
  int e = blockIdx.x * 256 + threadIdx.x;
  if (e < NEDGES) atomicAdd(&deg[dst[e]], 1);
}

// single block, 1024 threads = 16 waves; wave-shuffle prefix, 3 barriers/chunk
__global__ void k_scan(const int* __restrict__ deg, int* __restrict__ rowptr,
                       int* __restrict__ cursor) {
  __shared__ int wsum[16];
  __shared__ int s_run;
  int tid = threadIdx.x, lane = tid & 63, w = tid >> 6;
  if (tid == 0) s_run = 0;
  __syncthreads();
  for (int base = 0; base < NNODES; base += 1024) {
    int i = base + tid;
    int v = (i < NNODES) ? deg[i] : 0;
    int x = v;
    #pragma unroll
    for (int o = 1; o < 64; o <<= 1) {
      int t = __shfl_up(x, o);
      if (lane >= o) x += t;
    }
    if (lane == 63) wsum[w] = x;
    __syncthreads();
    if (w == 0 && lane < 16) {
      int t = wsum[lane];
      #pragma unroll
      for (int o = 1; o < 16; o <<= 1) {
        int u = __shfl_up(t, o);
        if (lane >= o) t += u;
      }
      wsum[lane] = t;
    }
    __syncthreads();
    int run = s_run;
    int add = run + (w > 0 ? wsum[w - 1] : 0);
    if (i < NNODES) { rowptr[i] = add + x - v; cursor[i] = add + x - v; }
    __syncthreads();
    if (tid == 0) s_run = run + wsum[15];
    __syncthreads();
  }
  if (tid == 0) rowptr[NNODES] = s_run;
}

__global__ void k_scatter(const int* __restrict__ dst, const int* __restrict__ src,
                          const int* __restrict__ rel_ids, int* __restrict__ cursor,
                          int* __restrict__ srcs, int* __restrict__ rels) {
  int e = blockIdx.x * 256 + threadIdx.x;
  if (e >= NEDGES) return;
  int p = atomicAdd(&cursor[dst[e]], 1);
  srcs[p] = src[e];
  rels[p] = rel_ids[e];
}

// ---------------- MFMA GEMM: C[M,NB] = A[M,KDIM] @ Bt[NB,KDIM]^T, epilogues ----------------
template<int KDIM, int NB, int EPI>
__global__ __launch_bounds__(256) void k_gemm(
    const __bf16* __restrict__ A, const __bf16* __restrict__ Bt,
    const float* __restrict__ bias, const __bf16* __restrict__ resid,
    __bf16* __restrict__ outb, float* __restrict__ outf) {
  __shared__ char sA[16384];   // 128 rows x 64 bf16, XOR-swizzled
  __shared__ char sB[16384];
  const int tid = threadIdx.x;
  const int lane = tid & 63, wid = tid >> 6;
  const int wr = wid >> 1, wc = wid & 1;
  const int lr = lane & 15, hi = lane >> 4;
  const long row0 = (long)blockIdx.x * 128;
  const long col0 = (long)blockIdx.y * 128;
  f32x4 acc[4][4] = {};

  for (int kc = 0; kc < KDIM / 64; ++kc) {
    __syncthreads();
    #pragma unroll
    for (int i = 0; i < 4; ++i) {
      int q = i * 256 + tid;            // 1024 16B chunks per tile
      int r = q >> 3, slot = q & 7;
      int sw = ((slot ^ (r & 7)) << 4); // swizzled byte offset within 128B row
      int4 av = *(const int4*)(A + (row0 + r) * KDIM + kc * 64 + slot * 8);
      *(int4*)(sA + r * 128 + sw) = av;
      int4 bv = *(const int4*)(Bt + (col0 + r) * KDIM + kc * 64 + slot * 8);
      *(int4*)(sB + r * 128 + sw) = bv;
    }
    __syncthreads();
    #pragma unroll
    for (int ks = 0; ks < 2; ++ks) {
      bf16x8 af[4], bfr[4];
      #pragma unroll
      for (int m = 0; m < 4; ++m) {
        int r = wr * 64 + m * 16 + lr;
        int cb = ((ks * 4 + hi) ^ (r & 7)) << 4;
        af[m] = *(const bf16x8*)(sA + r * 128 + cb);
      }
      #pragma unroll
      for (int n = 0; n < 4; ++n) {
        int r = wc * 64 + n * 16 + lr;
        int cb = ((ks * 4 + hi) ^ (r & 7)) << 4;
        bfr[n] = *(const bf16x8*)(sB + r * 128 + cb);
      }
      #pragma unroll
      for (int m = 0; m < 4; ++m)
        #pragma unroll
        for (int n = 0; n < 4; ++n)
          acc[m][n] = __builtin_amdgcn_mfma_f32_16x16x32_bf16(af[m], bfr[n], acc[m][n], 0, 0, 0);
    }
  }

  // C layout per frag: col = lane&15, row = (lane>>4)*4 + j
  #pragma unroll
  for (int m = 0; m < 4; ++m) {
    #pragma unroll
    for (int j = 0; j < 4; ++j) {
      long r = row0 + wr * 64 + m * 16 + hi * 4 + j;
      #pragma unroll
      for (int n = 0; n < 4; ++n) {
        long c = col0 + wc * 64 + n * 16 + lr;
        float v = acc[m][n][j];
        if (EPI == 0) {
          outb[r * NB + c] = (__bf16)v;
        } else if (EPI == 1) {
          outb[r * NB + c] = (__bf16)fmaxf(v + bias[c], 0.f);
        } else {
          outf[r * NB + c] = v + bias[c] + (float)resid[r * NB + c];
        }
      }
    }
  }
}

// ---------------- per-node attention scores from f (bf16) ----------------
__global__ void k_scores(const __bf16* __restrict__ f, const float* __restrict__ ah,
                         const float* __restrict__ at, float* __restrict__ ssrc,
                         float* __restrict__ sdst) {
  int lane = threadIdx.x & 63, wid = threadIdx.x >> 6;
  int n = blockIdx.x * 4 + wid;
  if (n >= NNODES) return;
  uint32 v = ((const uint32*)f)[n * 64 + lane];
  float x = b2f(v & 0xffffu), y = b2f(v >> 16);
  float2 a = ((const float2*)ah)[lane];
  float2 t = ((const float2*)at)[lane];
  float ps = x * a.x + y * a.y;
  float pt = x * t.x + y * t.y;
  #pragma unroll
  for (int o = 1; o < 8; o <<= 1) { ps += __shfl_xor(ps, o); pt += __shfl_xor(pt, o); }
  if ((lane & 7) == 0) {
    ssrc[n * 8 + (lane >> 3)] = ps;
    sdst[n * 8 + (lane >> 3)] = pt;
  }
}

// ---------------- edge softmax: online (m,den) pass + normalize pass ----------------
__global__ void k_softmax(const int* __restrict__ rowptr, const int* __restrict__ srcs,
                          const int* __restrict__ rels, const float* __restrict__ ssrc,
                          const float* __restrict__ sdst, const float* __restrict__ relsc,
                          float* __restrict__ att) {
  int lane = threadIdx.x & 63, wid = threadIdx.x >> 6;
  int n = blockIdx.x * 4 + wid;
  if (n >= NNODES) return;
  int start = rowptr[n], end = rowptr[n + 1];
  if (start == end) return;
  int hh = lane & 7, jj = lane >> 3;
  float sd = sdst[n * 8 + hh];
  float m = -1e30f, den = 0.f;
  // software-pipelined srcs load
  int jp = start + jj;
  int s_next = (jp < end) ? srcs[jp] : 0;
  int r_next = (relsc && jp < end) ? rels[jp] : 0;
  for (int j0 = start; j0 < end; j0 += 8) {
    int j = j0 + jj;
    int s = s_next, rl = r_next;
    int jn = j0 + 8 + jj;
    if (jn < end) {
      s_next = srcs[jn];
      if (relsc) r_next = rels[jn];
    }
    if (j < end) {
      float e = ssrc[s * 8 + hh] + sd;
      if (relsc) e += relsc[rl * 8 + hh];
      e = (e >= 0.f) ? e : 0.2f * e;
      att[j * 8 + hh] = e;
      float M = fmaxf(m, e);
      den = den * __expf(m - M) + __expf(e - M);
      m = M;
    }
  }
  // combine (m, den) across the 8 jj-groups (lane bits 3..5)
  #pragma unroll
  for (int o = 8; o < 64; o <<= 1) {
    float m2 = __shfl_xor(m, o), d2 = __shfl_xor(den, o);
    float M = fmaxf(m, m2);
    den = den * __expf(m - M) + d2 * __expf(m2 - M);
    m = M;
  }
  float inv = 1.f / (den + 1e-16f);
  for (int j0 = start; j0 < end; j0 += 8) {
    int j = j0 + jj;
    if (j < end) {
      float e = att[j * 8 + hh];
      att[j * 8 + hh] = __expf(e - m) * inv;
    }
  }
}

// ---------------- diffusion hop (bf16 feats, fp32 accum, batched-src pipeline) ----------------
__global__ __launch_bounds__(256) void k_hop(
    const int* __restrict__ rowptr, const int* __restrict__ srcs,
    const float* __restrict__ att, const __bf16* __restrict__ fin,
    const __bf16* __restrict__ f0, __bf16* __restrict__ fout) {
  int lane = threadIdx.x & 63, wid = threadIdx.x >> 6;
  int n = blockIdx.x * 4 + wid;
  if (n >= NNODES) return;
  int start = rowptr[n], end = rowptr[n + 1];
  int hsel = lane >> 3;
  float ax = 0.f, ay = 0.f;
  const uint32* fin2 = (const uint32*)fin;
  int j0 = start;
  if (j0 + 8 <= end) {
    // prefetch first batch: 8 srcs (lanes&7) + 64 att values (8 edges x 8 heads)
    int sv = srcs[j0 + (lane & 7)];
    float av = att[j0 * 8 + lane];
    for (; j0 + 8 <= end; j0 += 8) {
      int svc = sv; float avc = av;
      if (j0 + 16 <= end) {              // prefetch next batch while gathers fly
        sv = srcs[j0 + 8 + (lane & 7)];
        av = att[(j0 + 8) * 8 + lane];
      }
      #pragma unroll
      for (int k = 0; k < 8; ++k) {
        int s = __shfl(svc, k);
        float a = __shfl(avc, k * 8 + hsel);
        uint32 v = fin2[(long)s * 64 + lane];
        ax += a * b2f(v & 0xffffu);
        ay += a * b2f(v >> 16);
      }
    }
  }
  for (; j0 < end; ++j0) {               // tail (<8 edges)
    int s = srcs[j0];
    float a = att[j0 * 8 + hsel];
    uint32 v = fin2[(long)s * 64 + lane];
    ax += a * b2f(v & 0xffffu);
    ay += a * b2f(v >> 16);
  }
  uint32 z = ((const uint32*)f0)[n * 64 + lane];
  float ox = 0.15f * b2f(z & 0xffffu) + 0.85f * ax;
  float oy = 0.15f * b2f(z >> 16) + 0.85f * ay;
  ((uint32*)fout)[n * 64 + lane] = ((uint32)f2b(oy) << 16) | (uint32)f2b(ox);
}

// ---------------- LayerNorm ----------------
template<int INBF>
__global__ void k_ln(const void* __restrict__ xin, const __bf16* __restrict__ resid,
                     const float* __restrict__ g, const float* __restrict__ b,
                     float* __restrict__ outf, __bf16* __restrict__ outb) {
  int lane = threadIdx.x & 63, wid = threadIdx.x >> 6;
  int n = blockIdx.x * 4 + wid;
  if (n >= NNODES) return;
  float x, y;
  if (INBF) {
    uint32 v = ((const uint32*)xin)[n * 64 + lane];
    uint32 r = ((const uint32*)resid)[n * 64 + lane];
    x = b2f(v & 0xffffu) + b2f(r & 0xffffu);
    y = b2f(v >> 16) + b2f(r >> 16);
  } else {
    float2 v = ((const float2*)xin)[n * 64 + lane];
    x = v.x; y = v.y;
  }
  float s = x + y;
  #pragma unroll
  for (int o = 1; o < 64; o <<= 1) s += __shfl_xor(s, o);
  float mean = s * (1.f / 128.f);
  float dx = x - mean, dy = y - mean;
  float q = dx * dx + dy * dy;
  #pragma unroll
  for (int o = 1; o < 64; o <<= 1) q += __shfl_xor(q, o);
  float rs = rsqrtf(q * (1.f / 128.f) + 1e-5f);
  float2 gg = ((const float2*)g)[lane];
  float2 bb = ((const float2*)b)[lane];
  float ox = dx * rs * gg.x + bb.x;
  float oy = dy * rs * gg.y + bb.y;
  if (outf) ((float2*)outf)[n * 64 + lane] = make_float2(ox, oy);
  if (outb) ((uint32*)outb)[n * 64 + lane] = ((uint32)f2b(oy) << 16) | (uint32)f2b(ox);
}

// ---------------- final gather (fp32) ----------------
__global__ void k_gather(const int* __restrict__ ids, const float* __restrict__ h,
                         float* __restrict__ out) {
  int t = blockIdx.x * 256 + threadIdx.x;   // 512*32
  if (t >= 512 * 32) return;
  int b = t >> 5, c = t & 31;
  ((float4*)out)[t] = ((const float4*)h)[(long)ids[b] * 32 + c];
}

// ---------------- host side ----------------
struct LayerW {
  const float *Wh, *ah, *at, *g1, *b1, *w1, *c1, *w2, *c2, *g2, *b2;
};

extern "C" void kernel_launch(void* const* d_in, const int* in_sizes, int n_in,
                              void* d_out, int out_size, void* d_ws, size_t ws_size,
                              hipStream_t stream) {
  const int* ent_ids   = (const int*)d_in[0];
  const int* rel_ids   = (const int*)d_in[1];
  const int* arw_pos   = (const int*)d_in[2];
  const int* src       = (const int*)d_in[3];
  const int* dst       = (const int*)d_in[4];
  const int* batch_ids = (const int*)d_in[5];
  const float* ent_tab = (const float*)d_in[6];
  const float* rel_tab = (const float*)d_in[7];
  const float* pos_tab = (const float*)d_in[8];

  LayerW L0 = {(const float*)d_in[9],  (const float*)d_in[11], (const float*)d_in[12],
               (const float*)d_in[14], (const float*)d_in[15], (const float*)d_in[16],
               (const float*)d_in[17], (const float*)d_in[18], (const float*)d_in[19],
               (const float*)d_in[20], (const float*)d_in[21]};
  const float* l0_Wr = (const float*)d_in[10];
  const float* l0_ar = (const float*)d_in[13];
  LayerW L1 = {(const float*)d_in[22], (const float*)d_in[23], (const float*)d_in[24],
               (const float*)d_in[25], (const float*)d_in[26], (const float*)d_in[27],
               (const float*)d_in[28], (const float*)d_in[29], (const float*)d_in[30],
               (const float*)d_in[31], (const float*)d_in[32]};

  // ---- workspace carve (~130 MB) ----
  char* p = (char*)d_ws;
  auto alloc = [&](size_t bytes) { char* q = p; p += (bytes + 255) & ~(size_t)255; return q; };
  __bf16* hb = (__bf16*)alloc((size_t)NP * 128 * 2);
  __bf16* f  = (__bf16*)alloc((size_t)NP * 128 * 2);
  __bf16* fb = (__bf16*)alloc((size_t)NP * 128 * 2);   // must follow f (y aliases f+fb)
  __bf16* fa = (__bf16*)alloc((size_t)NP * 128 * 2);
  __bf16* ob = (__bf16*)alloc((size_t)NP * 128 * 2);
  char*   U  = alloc((size_t)NP * 512 * 2);            // union: att (fp32 E*8) | T (bf16 NP*512)
  float*  att = (float*)U;
  __bf16* T   = (__bf16*)U;
  float*  y   = (float*)f;                             // fp32 NP*128, spans f+fb
  float* ssrc  = (float*)alloc((size_t)NP * 8 * 4);
  float* sdst  = (float*)alloc((size_t)NP * 8 * 4);
  float* relsc = (float*)alloc(500 * 8 * 4);
  float* vr    = (float*)alloc(1024 * 4);
  __bf16* Wht0 = (__bf16*)alloc(128 * 128 * 2);
  __bf16* Wht1 = (__bf16*)alloc(128 * 128 * 2);
  __bf16* w1t0 = (__bf16*)alloc(512 * 128 * 2);
  __bf16* w1t1 = (__bf16*)alloc(512 * 128 * 2);
  __bf16* w2t0 = (__bf16*)alloc(128 * 512 * 2);
  __bf16* w2t1 = (__bf16*)alloc(128 * 512 * 2);
  int* deg    = (int*)alloc(NNODES * 4);
  int* rowptr = (int*)alloc((NNODES + 1) * 4);
  int* cursor = (int*)alloc(NNODES * 4);
  int* srcs   = (int*)alloc((size_t)NEDGES * 4);
  int* rels   = (int*)alloc((size_t)NEDGES * 4);

  // pad rows of GEMM A-inputs must be zero
  hipMemsetAsync(hb + (size_t)NNODES * 128, 0, (size_t)(NP - NNODES) * 128 * 2, stream);
  hipMemsetAsync(ob + (size_t)NNODES * 128, 0, (size_t)(NP - NNODES) * 128 * 2, stream);

  // embeddings, weight prep, relation score table
  k_embed<<<(NNODES * 32 + 255) / 256, 256, 0, stream>>>(ent_ids, arw_pos, ent_tab, pos_tab, hb);
  k_wt<<<dim3(8, 8), 256, 0, stream>>>(L0.Wh, Wht0, 128, 128);
  k_wt<<<dim3(8, 8), 256, 0, stream>>>(L1.Wh, Wht1, 128, 128);
  k_wt<<<dim3(32, 8), 256, 0, stream>>>(L0.w1, w1t0, 128, 512);
  k_wt<<<dim3(32, 8), 256, 0, stream>>>(L1.w1, w1t1, 128, 512);
  k_wt<<<dim3(8, 32), 256, 0, stream>>>(L0.w2, w2t0, 512, 128);
  k_wt<<<dim3(8, 32), 256, 0, stream>>>(L1.w2, w2t1, 512, 128);
  k_vr<<<1, 256, 0, stream>>>(l0_Wr, l0_ar, vr);
  k_relsc<<<16, 256, 0, stream>>>(rel_tab, vr, relsc);

  // CSR by dst
  hipMemsetAsync(deg, 0, NNODES * sizeof(int), stream);
  k_hist<<<NEDGES / 256, 256, 0, stream>>>(dst, deg);
  k_scan<<<1, 1024, 0, stream>>>(deg, rowptr, cursor);
  k_scatter<<<NEDGES / 256, 256, 0, stream>>>(dst, src, rel_ids, cursor, srcs, rels);

  const int NB4 = (NNODES + 3) / 4;
  for (int L = 0; L < 2; ++L) {
    const LayerW& W = L ? L1 : L0;
    const __bf16* Wht = L ? Wht1 : Wht0;
    const __bf16* w1t = L ? w1t1 : w1t0;
    const __bf16* w2t = L ? w2t1 : w2t0;
    const float* rsc  = L ? nullptr : relsc;

    k_gemm<128, 128, 0><<<dim3(391, 1), 256, 0, stream>>>(hb, Wht, nullptr, nullptr, f, nullptr);
    k_scores<<<NB4, 256, 0, stream>>>(f, W.ah, W.at, ssrc, sdst);
    k_softmax<<<NB4, 256, 0, stream>>>(rowptr, srcs, rels, ssrc, sdst, rsc, att);
    k_hop<<<NB4, 256, 0, stream>>>(rowptr, srcs, att, f, f, fa);
    k_hop<<<NB4, 256, 0, stream>>>(rowptr, srcs, att, fa, f, fb);
    k_hop<<<NB4, 256, 0, stream>>>(rowptr, srcs, att, fb, f, fa);
    k_ln<1><<<NB4, 256, 0, stream>>>(fa, hb, W.g1, W.b1, nullptr, ob);
    k_gemm<128, 512, 1><<<dim3(391, 4), 256, 0, stream>>>(ob, w1t, W.c1, nullptr, T, nullptr);
    k_gemm<512, 128, 2><<<dim3(391, 1), 256, 0, stream>>>(T, w2t, W.c2, ob, nullptr, y);
    k_ln<0><<<NB4, 256, 0, stream>>>(y, nullptr, W.g2, W.b2, y, hb);
  }

  k_gather<<<64, 256, 0, stream>>>(batch_ids, y, (float*)d_out);
}

// Round 4
// 575.301 us; speedup vs baseline: 2.5111x; 1.1225x over previous
//
#include <hip/hip_runtime.h>
#include <hip/hip_bf16.h>

#define NNODES 50000
#define NEDGES 800000
#define NP 50048            // 391 * 128, padded node count for unguarded GEMM tiles
#define DIM 128
#define HEADS 8
#define FFNDIM 512

typedef __bf16 bf16x8 __attribute__((ext_vector_type(8)));
typedef float f32x4 __attribute__((ext_vector_type(4)));
typedef unsigned int uint32;
typedef unsigned short ushort16;

__device__ __forceinline__ float b2f(uint32 u) {
  union { uint32 i; float f; } x; x.i = u << 16; return x.f;
}
__device__ __forceinline__ ushort16 f2b(float f) {
  __bf16 h = (__bf16)f; return __builtin_bit_cast(ushort16, h);
}

// ---------------- embedding: hb = bf16(ent_tab[ent_ids] + pos_tab[arw_pos]) ----------------
__global__ void k_embed(const int* __restrict__ ent_ids, const int* __restrict__ arw_pos,
                        const float* __restrict__ ent_tab, const float* __restrict__ pos_tab,
                        __bf16* __restrict__ hb) {
  int t = blockIdx.x * 256 + threadIdx.x;   // over N*32 float4s
  if (t >= NNODES * 32) return;
  int n = t >> 5, c = t & 31;
  float4 a = ((const float4*)ent_tab)[ent_ids[n] * 32 + c];
  float4 b = ((const float4*)pos_tab)[arw_pos[n] * 32 + c];
  ushort4 o;
  o.x = f2b(a.x + b.x); o.y = f2b(a.y + b.y);
  o.z = f2b(a.z + b.z); o.w = f2b(a.w + b.w);
  ((ushort4*)hb)[t] = o;
}

// ---------------- fused weight transpose+convert for all 6 matrices ----------------
__global__ void k_wt_all(const float* __restrict__ Wh0, const float* __restrict__ Wh1,
                         const float* __restrict__ w10, const float* __restrict__ w11,
                         const float* __restrict__ w20, const float* __restrict__ w21,
                         __bf16* __restrict__ T0, __bf16* __restrict__ T1,
                         __bf16* __restrict__ T2, __bf16* __restrict__ T3,
                         __bf16* __restrict__ T4, __bf16* __restrict__ T5) {
  int m = blockIdx.y;
  const float* W; __bf16* T; int R, lc;
  switch (m) {
    case 0: W = Wh0; T = T0; R = 128; lc = 7; break;
    case 1: W = Wh1; T = T1; R = 128; lc = 7; break;
    case 2: W = w10; T = T2; R = 128; lc = 9; break;
    case 3: W = w11; T = T3; R = 128; lc = 9; break;
    case 4: W = w20; T = T4; R = 512; lc = 7; break;
    default: W = w21; T = T5; R = 512; lc = 7; break;
  }
  int idx = blockIdx.x * 256 + threadIdx.x;
  if (idx >= (R << lc)) return;
  int r = idx >> lc, c = idx & ((1 << lc) - 1);
  T[(long)c * R + r] = (__bf16)W[idx];
}

// ---------------- relsc[r][h] = sum_d rel_tab[r][d] * (Wr@ar)[d][h] ----------------
__global__ void k_relsc(const float* __restrict__ Wr, const float* __restrict__ ar,
                        const float* __restrict__ rel_tab, float* __restrict__ relsc) {
  __shared__ float vr[1024];
  int tid = threadIdx.x;
  for (int i = tid; i < 1024; i += 256) {
    int d = i >> 3, hh = i & 7;
    float s = 0.f;
    #pragma unroll
    for (int k = 0; k < 16; ++k) s += Wr[d * 128 + hh * 16 + k] * ar[hh * 16 + k];
    vr[i] = s;
  }
  __syncthreads();
  int t = blockIdx.x * 256 + tid;
  if (t >= 500 * 8) return;
  int r = t >> 3, hh = t & 7;
  float s = 0.f;
  for (int d = 0; d < 128; ++d) s += rel_tab[r * 128 + d] * vr[d * 8 + hh];
  relsc[t] = s;
}

// ---------------- CSR build ----------------
__global__ void k_hist(const int* __restrict__ dst, int* __restrict__ deg) {
  int e = blockIdx.x * 256 + threadIdx.x;
  if (e < NEDGES) atomicAdd(&deg[dst[e]], 1);
}

__global__ void k_scan(const int* __restrict__ deg, int* __restrict__ rowptr,
                       int* __restrict__ cursor) {
  __shared__ int wsum[16];
  __shared__ int s_run;
  int tid = threadIdx.x, lane = tid & 63, w = tid >> 6;
  if (tid == 0) s_run = 0;
  __syncthreads();
  for (int base = 0; base < NNODES; base += 1024) {
    int i = base + tid;
    int v = (i < NNODES) ? deg[i] : 0;
    int x = v;
    #pragma unroll
    for (int o = 1; o < 64; o <<= 1) {
      int t = __shfl_up(x, o);
      if (lane >= o) x += t;
    }
    if (lane == 63) wsum[w] = x;
    __syncthreads();
    if (w == 0 && lane < 16) {
      int t = wsum[lane];
      #pragma unroll
      for (int o = 1; o < 16; o <<= 1) {
        int u = __shfl_up(t, o);
        if (lane >= o) t += u;
      }
      wsum[lane] = t;
    }
    __syncthreads();
    int run = s_run;
    int add = run + (w > 0 ? wsum[w - 1] : 0);
    if (i < NNODES) { rowptr[i] = add + x - v; cursor[i] = add + x - v; }
    __syncthreads();
    if (tid == 0) s_run = run + wsum[15];
    __syncthreads();
  }
  if (tid == 0) rowptr[NNODES] = s_run;
}

// pack src (low 16) | rel (high 16) -> one 4B random store per edge
__global__ void k_scatter(const int* __restrict__ dst, const int* __restrict__ src,
                          const int* __restrict__ rel_ids, int* __restrict__ cursor,
                          uint32* __restrict__ packed) {
  int e = blockIdx.x * 256 + threadIdx.x;
  if (e >= NEDGES) return;
  int p = atomicAdd(&cursor[dst[e]], 1);
  packed[p] = (uint32)src[e] | ((uint32)rel_ids[e] << 16);
}

// ---------------- MFMA GEMM: C[M,NB] = A[M,KDIM] @ Bt[NB,KDIM]^T, epilogues ----------------
template<int KDIM, int NB, int EPI>
__global__ __launch_bounds__(256) void k_gemm(
    const __bf16* __restrict__ A, const __bf16* __restrict__ Bt,
    const float* __restrict__ bias, const __bf16* __restrict__ resid,
    __bf16* __restrict__ outb, float* __restrict__ outf) {
  __shared__ char sA[16384];   // 128 rows x 64 bf16, XOR-swizzled
  __shared__ char sB[16384];
  const int tid = threadIdx.x;
  const int lane = tid & 63, wid = tid >> 6;
  const int wr = wid >> 1, wc = wid & 1;
  const int lr = lane & 15, hi = lane >> 4;
  const long row0 = (long)blockIdx.x * 128;
  const long col0 = (long)blockIdx.y * 128;
  f32x4 acc[4][4] = {};

  for (int kc = 0; kc < KDIM / 64; ++kc) {
    __syncthreads();
    #pragma unroll
    for (int i = 0; i < 4; ++i) {
      int q = i * 256 + tid;            // 1024 16B chunks per tile
      int r = q >> 3, slot = q & 7;
      int sw = ((slot ^ (r & 7)) << 4); // swizzled byte offset within 128B row
      int4 av = *(const int4*)(A + (row0 + r) * KDIM + kc * 64 + slot * 8);
      *(int4*)(sA + r * 128 + sw) = av;
      int4 bv = *(const int4*)(Bt + (col0 + r) * KDIM + kc * 64 + slot * 8);
      *(int4*)(sB + r * 128 + sw) = bv;
    }
    __syncthreads();
    #pragma unroll
    for (int ks = 0; ks < 2; ++ks) {
      bf16x8 af[4], bfr[4];
      #pragma unroll
      for (int m = 0; m < 4; ++m) {
        int r = wr * 64 + m * 16 + lr;
        int cb = ((ks * 4 + hi) ^ (r & 7)) << 4;
        af[m] = *(const bf16x8*)(sA + r * 128 + cb);
      }
      #pragma unroll
      for (int n = 0; n < 4; ++n) {
        int r = wc * 64 + n * 16 + lr;
        int cb = ((ks * 4 + hi) ^ (r & 7)) << 4;
        bfr[n] = *(const bf16x8*)(sB + r * 128 + cb);
      }
      #pragma unroll
      for (int m = 0; m < 4; ++m)
        #pragma unroll
        for (int n = 0; n < 4; ++n)
          acc[m][n] = __builtin_amdgcn_mfma_f32_16x16x32_bf16(af[m], bfr[n], acc[m][n], 0, 0, 0);
    }
  }

  #pragma unroll
  for (int m = 0; m < 4; ++m) {
    #pragma unroll
    for (int j = 0; j < 4; ++j) {
      long r = row0 + wr * 64 + m * 16 + hi * 4 + j;
      #pragma unroll
      for (int n = 0; n < 4; ++n) {
        long c = col0 + wc * 64 + n * 16 + lr;
        float v = acc[m][n][j];
        if (EPI == 0) {
          outb[r * NB + c] = (__bf16)v;
        } else if (EPI == 1) {
          outb[r * NB + c] = (__bf16)fmaxf(v + bias[c], 0.f);
        } else {
          outf[r * NB + c] = v + bias[c] + (float)resid[r * NB + c];
        }
      }
    }
  }
}

// ---------------- per-node attention scores from f (bf16) ----------------
__global__ void k_scores(const __bf16* __restrict__ f, const float* __restrict__ ah,
                         const float* __restrict__ at, float* __restrict__ ssrc,
                         float* __restrict__ sdst) {
  int lane = threadIdx.x & 63, wid = threadIdx.x >> 6;
  int n = blockIdx.x * 4 + wid;
  if (n >= NNODES) return;
  uint32 v = ((const uint32*)f)[n * 64 + lane];
  float x = b2f(v & 0xffffu), y = b2f(v >> 16);
  float2 a = ((const float2*)ah)[lane];
  float2 t = ((const float2*)at)[lane];
  float ps = x * a.x + y * a.y;
  float pt = x * t.x + y * t.y;
  #pragma unroll
  for (int o = 1; o < 8; o <<= 1) { ps += __shfl_xor(ps, o); pt += __shfl_xor(pt, o); }
  if ((lane & 7) == 0) {
    ssrc[n * 8 + (lane >> 3)] = ps;
    sdst[n * 8 + (lane >> 3)] = pt;
  }
}

// ---------------- edge softmax: register path (deg<=64), fallback 2-pass ----------------
__global__ void k_softmax(const int* __restrict__ rowptr, const uint32* __restrict__ packed,
                          const float* __restrict__ ssrc, const float* __restrict__ sdst,
                          const float* __restrict__ relsc, float* __restrict__ att) {
  int lane = threadIdx.x & 63, wid = threadIdx.x >> 6;
  int n = blockIdx.x * 4 + wid;
  if (n >= NNODES) return;
  int start = rowptr[n], end = rowptr[n + 1];
  if (start == end) return;
  int hh = lane & 7, jj = lane >> 3;
  float sd = sdst[n * 8 + hh];
  float m = -1e30f, den = 0.f;
  int deg = end - start;

  if (deg <= 64) {
    uint32 pk[8];
    float ev[8];
    int end1 = end - 1;
    #pragma unroll
    for (int t = 0; t < 8; ++t)
      pk[t] = packed[min(start + t * 8 + jj, end1)];          // batched loads
    #pragma unroll
    for (int t = 0; t < 8; ++t)
      ev[t] = ssrc[(pk[t] & 0xffffu) * 8 + hh];               // batched gathers
    #pragma unroll
    for (int t = 0; t < 8; ++t) {
      int j = start + t * 8 + jj;
      float e = ev[t] + sd;
      if (relsc) e += relsc[(pk[t] >> 16) * 8 + hh];
      e = (e >= 0.f) ? e : 0.2f * e;
      ev[t] = e;
      if (j < end) {
        float M = fmaxf(m, e);
        den = den * __expf(m - M) + __expf(e - M);
        m = M;
      }
    }
    #pragma unroll
    for (int o = 8; o < 64; o <<= 1) {
      float m2 = __shfl_xor(m, o), d2 = __shfl_xor(den, o);
      float M = fmaxf(m, m2);
      den = den * __expf(m - M) + d2 * __expf(m2 - M);
      m = M;
    }
    float inv = 1.f / (den + 1e-16f);
    #pragma unroll
    for (int t = 0; t < 8; ++t) {
      int j = start + t * 8 + jj;
      if (j < end) att[j * 8 + hh] = __expf(ev[t] - m) * inv;
    }
  } else {
    for (int j0 = start; j0 < end; j0 += 8) {
      int j = j0 + jj;
      if (j < end) {
        uint32 p2 = packed[j];
        float e = ssrc[(p2 & 0xffffu) * 8 + hh] + sd;
        if (relsc) e += relsc[(p2 >> 16) * 8 + hh];
        e = (e >= 0.f) ? e : 0.2f * e;
        att[j * 8 + hh] = e;
        float M = fmaxf(m, e);
        den = den * __expf(m - M) + __expf(e - M);
        m = M;
      }
    }
    #pragma unroll
    for (int o = 8; o < 64; o <<= 1) {
      float m2 = __shfl_xor(m, o), d2 = __shfl_xor(den, o);
      float M = fmaxf(m, m2);
      den = den * __expf(m - M) + d2 * __expf(m2 - M);
      m = M;
    }
    float inv = 1.f / (den + 1e-16f);
    for (int j0 = start; j0 < end; j0 += 8) {
      int j = j0 + jj;
      if (j < end) {
        float e = att[j * 8 + hh];
        att[j * 8 + hh] = __expf(e - m) * inv;
      }
    }
  }
}

// ---------------- diffusion hop: 16-edge branchless batches; FINAL fuses LN+resid ----------------
template<int FINAL>
__global__ __launch_bounds__(256) void k_hop(
    const int* __restrict__ rowptr, const uint32* __restrict__ packed,
    const float* __restrict__ att, const __bf16* __restrict__ fin,
    const __bf16* __restrict__ f0, __bf16* __restrict__ fout,
    const __bf16* __restrict__ resid, const float* __restrict__ g,
    const float* __restrict__ b) {
  int lane = threadIdx.x & 63, wid = threadIdx.x >> 6;
  int n = blockIdx.x * 4 + wid;
  if (n >= NNODES) return;
  int start = rowptr[n], end = rowptr[n + 1];
  int hsel = lane >> 3;
  float ax = 0.f, ay = 0.f;
  const uint32* fin2 = (const uint32*)fin;
  if (start < end) {
    int end1 = end - 1;
    int e8 = end * 8 - 1;
    uint32 sv = packed[min(start + (lane & 15), end1)];
    float av0 = att[min(start * 8 + lane, e8)];
    float av1 = att[min(start * 8 + 64 + lane, e8)];
    for (int j0 = start; j0 < end; j0 += 16) {
      uint32 svc = sv; float a0 = av0, a1 = av1;
      int jn = j0 + 16;
      if (jn < end) {                    // prefetch next batch while gathers fly
        sv = packed[min(jn + (lane & 15), end1)];
        av0 = att[min(jn * 8 + lane, e8)];
        av1 = att[min(jn * 8 + 64 + lane, e8)];
      }
      #pragma unroll
      for (int k = 0; k < 16; ++k) {
        float a = (k < 8) ? __shfl(a0, k * 8 + hsel) : __shfl(a1, (k - 8) * 8 + hsel);
        a = (j0 + k < end) ? a : 0.f;    // branchless mask (clamped addr stays valid)
        int s = (int)(__shfl(svc, k) & 0xffffu);
        uint32 v = fin2[(long)s * 64 + lane];
        ax += a * b2f(v & 0xffffu);
        ay += a * b2f(v >> 16);
      }
    }
  }
  uint32 z = ((const uint32*)f0)[n * 64 + lane];
  float ox = 0.15f * b2f(z & 0xffffu) + 0.85f * ax;
  float oy = 0.15f * b2f(z >> 16) + 0.85f * ay;
  if (!FINAL) {
    ((uint32*)fout)[n * 64 + lane] = ((uint32)f2b(oy) << 16) | (uint32)f2b(ox);
  } else {
    uint32 rz = ((const uint32*)resid)[n * 64 + lane];
    float x = ox + b2f(rz & 0xffffu);
    float y = oy + b2f(rz >> 16);
    float s = x + y;
    #pragma unroll
    for (int o = 1; o < 64; o <<= 1) s += __shfl_xor(s, o);
    float mean = s * (1.f / 128.f);
    float dx = x - mean, dy = y - mean;
    float q = dx * dx + dy * dy;
    #pragma unroll
    for (int o = 1; o < 64; o <<= 1) q += __shfl_xor(q, o);
    float rs2 = rsqrtf(q * (1.f / 128.f) + 1e-5f);
    float2 gg = ((const float2*)g)[lane];
    float2 bb = ((const float2*)b)[lane];
    float o1 = dx * rs2 * gg.x + bb.x;
    float o2 = dy * rs2 * gg.y + bb.y;
    ((uint32*)fout)[n * 64 + lane] = ((uint32)f2b(o2) << 16) | (uint32)f2b(o1);
  }
}

// ---------------- LayerNorm (fp32 in, fp32 + bf16 out) ----------------
__global__ void k_ln0(const float* __restrict__ xin, const float* __restrict__ g,
                      const float* __restrict__ b, float* __restrict__ outf,
                      __bf16* __restrict__ outb) {
  int lane = threadIdx.x & 63, wid = threadIdx.x >> 6;
  int n = blockIdx.x * 4 + wid;
  if (n >= NNODES) return;
  float2 v = ((const float2*)xin)[n * 64 + lane];
  float x = v.x, y = v.y;
  float s = x + y;
  #pragma unroll
  for (int o = 1; o < 64; o <<= 1) s += __shfl_xor(s, o);
  float mean = s * (1.f / 128.f);
  float dx = x - mean, dy = y - mean;
  float q = dx * dx + dy * dy;
  #pragma unroll
  for (int o = 1; o < 64; o <<= 1) q += __shfl_xor(q, o);
  float rs = rsqrtf(q * (1.f / 128.f) + 1e-5f);
  float2 gg = ((const float2*)g)[lane];
  float2 bb = ((const float2*)b)[lane];
  float ox = dx * rs * gg.x + bb.x;
  float oy = dy * rs * gg.y + bb.y;
  ((float2*)outf)[n * 64 + lane] = make_float2(ox, oy);
  ((uint32*)outb)[n * 64 + lane] = ((uint32)f2b(oy) << 16) | (uint32)f2b(ox);
}

// ---------------- final gather (fp32) ----------------
__global__ void k_gather(const int* __restrict__ ids, const float* __restrict__ h,
                         float* __restrict__ out) {
  int t = blockIdx.x * 256 + threadIdx.x;   // 512*32
  if (t >= 512 * 32) return;
  int b = t >> 5, c = t & 31;
  ((float4*)out)[t] = ((const float4*)h)[(long)ids[b] * 32 + c];
}

// ---------------- host side ----------------
struct LayerW {
  const float *Wh, *ah, *at, *g1, *b1, *w1, *c1, *w2, *c2, *g2, *b2;
};

extern "C" void kernel_launch(void* const* d_in, const int* in_sizes, int n_in,
                              void* d_out, int out_size, void* d_ws, size_t ws_size,
                              hipStream_t stream) {
  const int* ent_ids   = (const int*)d_in[0];
  const int* rel_ids   = (const int*)d_in[1];
  const int* arw_pos   = (const int*)d_in[2];
  const int* src       = (const int*)d_in[3];
  const int* dst       = (const int*)d_in[4];
  const int* batch_ids = (const int*)d_in[5];
  const float* ent_tab = (const float*)d_in[6];
  const float* rel_tab = (const float*)d_in[7];
  const float* pos_tab = (const float*)d_in[8];

  LayerW L0 = {(const float*)d_in[9],  (const float*)d_in[11], (const float*)d_in[12],
               (const float*)d_in[14], (const float*)d_in[15], (const float*)d_in[16],
               (const float*)d_in[17], (const float*)d_in[18], (const float*)d_in[19],
               (const float*)d_in[20], (const float*)d_in[21]};
  const float* l0_Wr = (const float*)d_in[10];
  const float* l0_ar = (const float*)d_in[13];
  LayerW L1 = {(const float*)d_in[22], (const float*)d_in[23], (const float*)d_in[24],
               (const float*)d_in[25], (const float*)d_in[26], (const float*)d_in[27],
               (const float*)d_in[28], (const float*)d_in[29], (const float*)d_in[30],
               (const float*)d_in[31], (const float*)d_in[32]};

  // ---- workspace carve (~130 MB) ----
  char* p = (char*)d_ws;
  auto alloc = [&](size_t bytes) { char* q = p; p += (bytes + 255) & ~(size_t)255; return q; };
  __bf16* hb = (__bf16*)alloc((size_t)NP * 128 * 2);
  __bf16* f  = (__bf16*)alloc((size_t)NP * 128 * 2);
  __bf16* fb = (__bf16*)alloc((size_t)NP * 128 * 2);   // must follow f (y aliases f+fb)
  __bf16* fa = (__bf16*)alloc((size_t)NP * 128 * 2);
  __bf16* ob = (__bf16*)alloc((size_t)NP * 128 * 2);
  char*   U  = alloc((size_t)NP * 512 * 2);            // union: att (fp32 E*8) | T (bf16 NP*512)
  float*  att = (float*)U;
  __bf16* T   = (__bf16*)U;
  float*  y   = (float*)f;                             // fp32 NP*128, spans f+fb
  float* ssrc  = (float*)alloc((size_t)NP * 8 * 4);
  float* sdst  = (float*)alloc((size_t)NP * 8 * 4);
  float* relsc = (float*)alloc(500 * 8 * 4);
  __bf16* Wht0 = (__bf16*)alloc(128 * 128 * 2);
  __bf16* Wht1 = (__bf16*)alloc(128 * 128 * 2);
  __bf16* w1t0 = (__bf16*)alloc(512 * 128 * 2);
  __bf16* w1t1 = (__bf16*)alloc(512 * 128 * 2);
  __bf16* w2t0 = (__bf16*)alloc(128 * 512 * 2);
  __bf16* w2t1 = (__bf16*)alloc(128 * 512 * 2);
  int* deg    = (int*)alloc(NNODES * 4);
  int* rowptr = (int*)alloc((NNODES + 1) * 4);
  int* cursor = (int*)alloc(NNODES * 4);
  uint32* packed = (uint32*)alloc((size_t)NEDGES * 4);

  // pad rows of GEMM A-inputs must be zero
  hipMemsetAsync(hb + (size_t)NNODES * 128, 0, (size_t)(NP - NNODES) * 128 * 2, stream);
  hipMemsetAsync(ob + (size_t)NNODES * 128, 0, (size_t)(NP - NNODES) * 128 * 2, stream);

  // embeddings, weight prep, relation score table
  k_embed<<<(NNODES * 32 + 255) / 256, 256, 0, stream>>>(ent_ids, arw_pos, ent_tab, pos_tab, hb);
  k_wt_all<<<dim3(256, 6), 256, 0, stream>>>(L0.Wh, L1.Wh, L0.w1, L1.w1, L0.w2, L1.w2,
                                             Wht0, Wht1, w1t0, w1t1, w2t0, w2t1);
  k_relsc<<<16, 256, 0, stream>>>(l0_Wr, l0_ar, rel_tab, relsc);

  // CSR by dst
  hipMemsetAsync(deg, 0, NNODES * sizeof(int), stream);
  k_hist<<<NEDGES / 256, 256, 0, stream>>>(dst, deg);
  k_scan<<<1, 1024, 0, stream>>>(deg, rowptr, cursor);
  k_scatter<<<NEDGES / 256, 256, 0, stream>>>(dst, src, rel_ids, cursor, packed);

  const int NB4 = (NNODES + 3) / 4;
  for (int L = 0; L < 2; ++L) {
    const LayerW& W = L ? L1 : L0;
    const __bf16* Wht = L ? Wht1 : Wht0;
    const __bf16* w1t = L ? w1t1 : w1t0;
    const __bf16* w2t = L ? w2t1 : w2t0;
    const float* rsc  = L ? nullptr : relsc;

    k_gemm<128, 128, 0><<<dim3(391, 1), 256, 0, stream>>>(hb, Wht, nullptr, nullptr, f, nullptr);
    k_scores<<<NB4, 256, 0, stream>>>(f, W.ah, W.at, ssrc, sdst);
    k_softmax<<<NB4, 256, 0, stream>>>(rowptr, packed, ssrc, sdst, rsc, att);
    k_hop<0><<<NB4, 256, 0, stream>>>(rowptr, packed, att, f, f, fa, nullptr, nullptr, nullptr);
    k_hop<0><<<NB4, 256, 0, stream>>>(rowptr, packed, att, fa, f, fb, nullptr, nullptr, nullptr);
    k_hop<1><<<NB4, 256, 0, stream>>>(rowptr, packed, att, fb, f, ob, hb, W.g1, W.b1);
    k_gemm<128, 512, 1><<<dim3(391, 4), 256, 0, stream>>>(ob, w1t, W.c1, nullptr, T, nullptr);
    k_gemm<512, 128, 2><<<dim3(391, 1), 256, 0, stream>>>(T, w2t, W.c2, ob, nullptr, y);
    k_ln0<<<NB4, 256, 0, stream>>>(y, W.g2, W.b2, y, hb);
  }

  k_gather<<<64, 256, 0, stream>>>(batch_ids, y, (float*)d_out);
}